// Round 8
// baseline (961.615 us; speedup 1.0000x reference)
//
#include <hip/hip_runtime.h>
#include <math.h>

#define ALPHA 0.2f

__device__ __forceinline__ float leaky(float x){ return x > 0.f ? x : ALPHA*x; }
__device__ __forceinline__ float bcast(float v, int l){
  return __int_as_float(__builtin_amdgcn_readlane(__float_as_int(v), l));
}
__device__ __forceinline__ int rdlane_i(int v, int l){
  return __builtin_amdgcn_readlane(v, l);
}

static inline int cdiv(long a, long b){ return (int)((a + b - 1)/b); }

// dst histograms for both graphs in one launch
__global__ void k_count_dual(const int* __restrict__ dstA, int nA, int* __restrict__ cntA,
                             const int* __restrict__ dstB, int nB, int* __restrict__ cntB){
  int i = blockIdx.x*blockDim.x + threadIdx.x;
  if(i < nA) atomicAdd(&cntA[dstA[i]], 1);
  else if(i < nA + nB) atomicAdd(&cntB[dstB[i - nA]], 1);
}

__global__ void k_dinv_dual(const int* __restrict__ cntA, float* __restrict__ dinvA, int nA,
                            const int* __restrict__ cntB, float* __restrict__ dinvB, int nB){
  int i = blockIdx.x*blockDim.x + threadIdx.x;
  if(i < nA) dinvA[i] = rsqrtf((float)(cntA[i]+1));
  else if(i < nA + nB){ int j = i - nA; dinvB[j] = rsqrtf((float)(cntB[j]+1)); }
}

// ---- exclusive scan (dual-array, 3 stages) ----
__global__ void k_scan1_dual(const int* __restrict__ cntA, int* __restrict__ exA,
                             int* __restrict__ bsA, int nA, int nbA,
                             const int* __restrict__ cntB, int* __restrict__ exB,
                             int* __restrict__ bsB, int nB){
  const int* cnt; int* ex; int* bs; int n; int blk;
  if((int)blockIdx.x < nbA){ cnt=cntA; ex=exA; bs=bsA; n=nA; blk=blockIdx.x; }
  else                     { cnt=cntB; ex=exB; bs=bsB; n=nB; blk=blockIdx.x-nbA; }
  __shared__ int s[256];
  int i = blk*256 + threadIdx.x;
  int v = (i<n) ? cnt[i] : 0;
  s[threadIdx.x]=v; __syncthreads();
  #pragma unroll
  for(int off=1; off<256; off<<=1){
    int t = (threadIdx.x>=(unsigned)off) ? s[threadIdx.x-off] : 0;
    __syncthreads();
    s[threadIdx.x]+=t;
    __syncthreads();
  }
  if(i<n) ex[i] = s[threadIdx.x]-v;
  if(threadIdx.x==255) bs[blk]=s[255];
}

__global__ void k_scan2_dual(int* __restrict__ bsA, int nbA, int* __restrict__ bsB, int nbB){
  __shared__ int s[1024];
  {
    int v = ((int)threadIdx.x<nbA) ? bsA[threadIdx.x] : 0;
    s[threadIdx.x]=v; __syncthreads();
    #pragma unroll
    for(int off=1; off<1024; off<<=1){
      int t = (threadIdx.x>=(unsigned)off) ? s[threadIdx.x-off] : 0;
      __syncthreads();
      s[threadIdx.x]+=t;
      __syncthreads();
    }
    if((int)threadIdx.x<nbA) bsA[threadIdx.x] = s[threadIdx.x]-v;
    __syncthreads();
  }
  {
    int v = ((int)threadIdx.x<nbB) ? bsB[threadIdx.x] : 0;
    s[threadIdx.x]=v; __syncthreads();
    #pragma unroll
    for(int off=1; off<1024; off<<=1){
      int t = (threadIdx.x>=(unsigned)off) ? s[threadIdx.x-off] : 0;
      __syncthreads();
      s[threadIdx.x]+=t;
      __syncthreads();
    }
    if((int)threadIdx.x<nbB) bsB[threadIdx.x] = s[threadIdx.x]-v;
  }
}

// finalize rowptr; also emit bucket cursors bcur[b] = rowptr[64*b]
__global__ void k_scan3_dual(int* __restrict__ exA, const int* __restrict__ bsA,
                             int nA, int nbA, int totA, int* __restrict__ bcurA,
                             int* __restrict__ exB, const int* __restrict__ bsB,
                             int nB, int totB, int* __restrict__ bcurB){
  int* ex; const int* bs; int n; int blk; int tot; int* bcur;
  if((int)blockIdx.x < nbA){ ex=exA; bs=bsA; n=nA; blk=blockIdx.x; tot=totA; bcur=bcurA; }
  else                     { ex=exB; bs=bsB; n=nB; blk=blockIdx.x-nbA; tot=totB; bcur=bcurB; }
  int i = blk*256 + threadIdx.x;
  if(i<n){
    int v = ex[i] + (blk>0 ? bs[blk] : 0);
    ex[i] = v;
    if((i&63)==0) bcur[i>>6] = v;
  }
  if(blk==0 && threadIdx.x==0) ex[n] = tot;
}

// pass 1: scatter (src,dst) records into per-bucket regions (bucket = 64 dst nodes).
// Bucket regions are contiguous (base = rowptr[64b]); per-bucket cursor append keeps
// each bucket's write stream sequential -> no partial-line writeback amplification.
__global__ void k_bucket_dual(const int* __restrict__ eiA, int nA,
                              int* __restrict__ bcurA, int2* __restrict__ tmpA,
                              const int* __restrict__ eiB, int nB,
                              int* __restrict__ bcurB, int2* __restrict__ tmpB){
  int i = blockIdx.x*blockDim.x + threadIdx.x;
  if(i < nA){
    int s = eiA[i], d = eiA[nA+i];
    int pos = atomicAdd(&bcurA[d>>6], 1);
    tmpA[pos] = make_int2(s, d);
  } else if(i < nA + nB){
    int j = i - nA;
    int s = eiB[j], d = eiB[nB+j];
    int pos = atomicAdd(&bcurB[d>>6], 1);
    tmpB[pos] = make_int2(s, d);
  }
}

// pass 2: one block per bucket; LDS cursors; sequential reads, writes land in the
// bucket's contiguous ce window (L2-local).
__global__ __launch_bounds__(256) void k_place_dual(
    const int2* __restrict__ tmpA, const int* __restrict__ rpA, int* __restrict__ ceA,
    int nnA, int nbkA,
    const int2* __restrict__ tmpB, const int* __restrict__ rpB, int* __restrict__ ceB,
    int nnB){
  const int2* tmp; const int* rp; int* ce; int nn; int b;
  if((int)blockIdx.x < nbkA){ tmp=tmpA; rp=rpA; ce=ceA; nn=nnA; b=blockIdx.x; }
  else                      { tmp=tmpB; rp=rpB; ce=ceB; nn=nnB; b=blockIdx.x-nbkA; }
  __shared__ int lcur[64];
  __shared__ int lrp[65];
  int base = b<<6;
  int t = threadIdx.x;
  if(t<65){
    int node = base + t; if(node > nn) node = nn;
    lrp[t] = rp[node];
    if(t<64) lcur[t] = 0;
  }
  __syncthreads();
  int start = lrp[0], end = lrp[64];
  for(int j = start + t; j < end; j += 256){
    int2 r = tmp[j];
    int dl = r.y - base;
    int pos = lrp[dl] + atomicAdd(&lcur[dl], 1);
    ce[pos] = r.x;
  }
}

// input linear: out[r][c] = leaky(X[r] . W[:,c] + b[c]), K=128; wave per row,
// W column in VGPRs, X broadcast via readlane; grid-stride.
__global__ __launch_bounds__(256) void k_linear128(const float* __restrict__ X,
                                                   const float* __restrict__ W,
                                                   const float* __restrict__ b,
                                                   float* __restrict__ out, int rows){
  int lane = threadIdx.x & 63;
  int gw = (blockIdx.x*256 + threadIdx.x) >> 6;
  int nw = (gridDim.x*256) >> 6;
  float wcol[128];
  #pragma unroll
  for(int k=0;k<128;k++) wcol[k] = W[(size_t)k*64 + lane];
  float bl = b[lane];
  for(int row = gw; row < rows; row += nw){
    const float* xr = X + (size_t)row*128;
    float a0=0.f, a1=0.f, a2=0.f, a3=0.f;
    #pragma unroll
    for(int kk=0; kk<128; kk+=64){
      float xv = xr[kk + lane];
      #pragma unroll
      for(int k=0;k<64;k+=4){
        a0 = fmaf(bcast(xv, k+0), wcol[kk+k+0], a0);
        a1 = fmaf(bcast(xv, k+1), wcol[kk+k+1], a1);
        a2 = fmaf(bcast(xv, k+2), wcol[kk+k+2], a2);
        a3 = fmaf(bcast(xv, k+3), wcol[kk+k+3], a3);
      }
    }
    out[(size_t)row*64 + lane] = leaky(((a0+a1)+(a2+a3)) + bl);
  }
}

// fused GCN layer, using Agg(H·W) = Agg(H)·W:
//   av[c]  = h[i][c]*dinv[i]^2 + sum_edges h[s][c]*dinv[s]*dinv[i]   (aggregate raw h)
//   r[c']  = sum_c av[c]*W[c][c'] + b[c']                            (readlane matvec)
//   out    = leaky(r)            (CLS=1: -> classifier + log_softmax into out[i][0..1])
template<int CLS>
__global__ __launch_bounds__(256) void k_layer(const float* __restrict__ h,
                const int* __restrict__ rowptr, const int* __restrict__ ce,
                const float* __restrict__ dinv,
                const float* __restrict__ W, const float* __restrict__ b,
                const float* __restrict__ Wc, const float* __restrict__ bc,
                float* __restrict__ out, int n){
  int lane = threadIdx.x & 63;
  int gw = (blockIdx.x*256 + threadIdx.x) >> 6;
  int nw = (gridDim.x*256) >> 6;
  float wcol[64];
  #pragma unroll
  for(int k=0;k<64;k++) wcol[k] = W[(size_t)k*64 + lane];
  float bl = b[lane];
  float wc0 = CLS ? Wc[lane*2+0] : 0.f;
  float wc1 = CLS ? Wc[lane*2+1] : 0.f;
  int lane8 = lane & 7;
  for(int i = gw; i < n; i += nw){
    float dv = dinv[i];
    int start = rowptr[i], end = rowptr[i+1];
    float a0 = h[(size_t)i*64+lane]*dv*dv, a1=0.f, a2=0.f, a3=0.f;
    for(int j = start; j < end; j += 8){
      int idx = j + lane8; idx = (idx < end) ? idx : end-1;
      int sv = ce[idx];
      float dwv = dinv[sv];
      #pragma unroll
      for(int k=0;k<8;k+=4){
        int   s0 = rdlane_i(sv,k+0), s1 = rdlane_i(sv,k+1);
        int   s2 = rdlane_i(sv,k+2), s3 = rdlane_i(sv,k+3);
        float w0 = bcast(dwv,k+0), w1 = bcast(dwv,k+1);
        float w2 = bcast(dwv,k+2), w3 = bcast(dwv,k+3);
        float g0 = h[(size_t)s0*64+lane], g1 = h[(size_t)s1*64+lane];
        float g2 = h[(size_t)s2*64+lane], g3 = h[(size_t)s3*64+lane];
        w0 = (j+k+0 < end) ? w0*dv : 0.f;
        w1 = (j+k+1 < end) ? w1*dv : 0.f;
        w2 = (j+k+2 < end) ? w2*dv : 0.f;
        w3 = (j+k+3 < end) ? w3*dv : 0.f;
        a0 = fmaf(g0,w0,a0); a1 = fmaf(g1,w1,a1);
        a2 = fmaf(g2,w2,a2); a3 = fmaf(g3,w3,a3);
      }
    }
    float av = (a0+a1)+(a2+a3);
    float r0=0.f,r1=0.f,r2=0.f,r3=0.f;
    #pragma unroll
    for(int k=0;k<64;k+=4){
      r0 = fmaf(bcast(av,k+0), wcol[k+0], r0);
      r1 = fmaf(bcast(av,k+1), wcol[k+1], r1);
      r2 = fmaf(bcast(av,k+2), wcol[k+2], r2);
      r3 = fmaf(bcast(av,k+3), wcol[k+3], r3);
    }
    float r = ((r0+r1)+(r2+r3)) + bl;
    if(!CLS){
      out[(size_t)i*64+lane] = leaky(r);
    } else {
      float zv = leaky(r);
      float s0 = zv*wc0, s1 = zv*wc1;
      #pragma unroll
      for(int off2=32; off2; off2>>=1){
        s0 += __shfl_down(s0, off2);
        s1 += __shfl_down(s1, off2);
      }
      if(lane==0){
        float l0 = s0 + bc[0], l1 = s1 + bc[1];
        float m = fmaxf(l0,l1);
        float lse = m + logf(expf(l0-m)+expf(l1-m));
        out[(size_t)i*2+0] = l0 - lse;
        out[(size_t)i*2+1] = l1 - lse;
      }
    }
  }
}

extern "C" void kernel_launch(void* const* d_in, const int* in_sizes, int n_in,
                              void* d_out, int out_size, void* d_ws, size_t ws_size,
                              hipStream_t stream) {
  const float* x      = (const float*)d_in[0];
  const float* meta_x = (const float*)d_in[1];
  const int*   ei     = (const int*)d_in[2];
  const int*   mei    = (const int*)d_in[3];
  const float* W_lin  = (const float*)d_in[4];
  const float* b_lin  = (const float*)d_in[5];
  const float* W_meta = (const float*)d_in[6];
  const float* b_meta = (const float*)d_in[7];
  const float* Ws     = (const float*)d_in[8];
  const float* bs_    = (const float*)d_in[9];
  const float* W_mg   = (const float*)d_in[10];
  const float* b_mg   = (const float*)d_in[11];
  const float* W_cls  = (const float*)d_in[12];
  const float* b_cls  = (const float*)d_in[13];
  float* out = (float*)d_out;

  const int N  = in_sizes[0]/128;
  const int M  = in_sizes[1]/128;
  const int E  = in_sizes[2]/2;
  const int ME = in_sizes[3]/2;
  const int NM = N + M;

  char* ws = (char*)d_ws;
  size_t off = 0;
  auto alloc = [&](size_t bytes)->void*{ void* p = ws + off; off += (bytes + 255) & ~(size_t)255; return p; };
  float* zbuf = (float*)alloc((size_t)NM*64*4);   // concat(h3, mh), activated
  float* P0   = (float*)alloc((size_t)N*64*4);
  float* P1   = (float*)alloc((size_t)N*64*4);
  int*  ce_g  = (int*)alloc((size_t)E*4);         // CSR edges (src), main
  int*  ce_m  = (int*)alloc((size_t)ME*4);        // CSR edges (src), meta
  int2* tmp_g = (int2*)alloc((size_t)E*8);        // bucketed (src,dst) records
  int2* tmp_m = (int2*)alloc((size_t)ME*8);
  char* zero_base = ws + off;
  int* cnt_g  = (int*)alloc((size_t)N*4);
  int* cnt_m  = (int*)alloc((size_t)NM*4);
  size_t zero_bytes = (ws + off) - zero_base;
  int* rowptr_g = (int*)alloc((size_t)(N+1)*4);
  int* rowptr_m = (int*)alloc((size_t)(NM+1)*4);
  const int NBg = cdiv(N, 64), NBm = cdiv(NM, 64);
  int* bcur_g = (int*)alloc((size_t)NBg*4);
  int* bcur_m = (int*)alloc((size_t)NBm*4);
  int* bsumA  = (int*)alloc(1024*4);
  int* bsumB  = (int*)alloc(1024*4);
  float* dinv_g = (float*)alloc((size_t)N*4);
  float* dinv_m = (float*)alloc((size_t)NM*4);
  (void)ws_size; (void)n_in; (void)out_size;

  const int B = 256;
  const int nbA = cdiv(N, 256), nbB = cdiv(NM, 256);

  (void)hipMemsetAsync(zero_base, 0, zero_bytes, stream);

  // degree histograms + dinv (self-loop => deg = cnt+1)
  k_count_dual<<<cdiv((long)E+ME,B), B, 0, stream>>>(ei+E, E, cnt_g, mei+ME, ME, cnt_m);
  k_dinv_dual<<<cdiv((long)N+NM,B), B, 0, stream>>>(cnt_g, dinv_g, N, cnt_m, dinv_m, NM);

  // rowptr via scan; bcur[b]=rowptr[64b] emitted in scan3
  k_scan1_dual<<<nbA+nbB, 256, 0, stream>>>(cnt_g, rowptr_g, bsumA, N, nbA,
                                            cnt_m, rowptr_m, bsumB, NM);
  k_scan2_dual<<<1, 1024, 0, stream>>>(bsumA, nbA, bsumB, nbB);
  k_scan3_dual<<<nbA+nbB, 256, 0, stream>>>(rowptr_g, bsumA, N, nbA, E, bcur_g,
                                            rowptr_m, bsumB, NM, ME, bcur_m);

  // two-pass binned CSR fill
  k_bucket_dual<<<cdiv((long)E+ME,B), B, 0, stream>>>(ei, E, bcur_g, tmp_g,
                                                      mei, ME, bcur_m, tmp_m);
  k_place_dual<<<NBg+NBm, 256, 0, stream>>>(tmp_g, rowptr_g, ce_g, N, NBg,
                                            tmp_m, rowptr_m, ce_m, NM);

  // input linears (activated)
  k_linear128<<<1024, 256, 0, stream>>>(x,      W_lin,  b_lin,  P0,                  N);
  k_linear128<<<1024, 256, 0, stream>>>(meta_x, W_meta, b_meta, zbuf + (size_t)N*64, M);

  // 3 fused GCN layers (aggregate + matvec + bias + leaky)
  k_layer<0><<<1024, 256, 0, stream>>>(P0, rowptr_g, ce_g, dinv_g,
                                       Ws,              bs_,      nullptr, nullptr, P1,   N);
  k_layer<0><<<1024, 256, 0, stream>>>(P1, rowptr_g, ce_g, dinv_g,
                                       Ws + 64*64,      bs_ + 64, nullptr, nullptr, P0,   N);
  k_layer<0><<<1024, 256, 0, stream>>>(P0, rowptr_g, ce_g, dinv_g,
                                       Ws + 2*64*64,    bs_ +128, nullptr, nullptr, zbuf, N);

  // meta layer + classifier + log_softmax fused
  k_layer<1><<<1024, 256, 0, stream>>>(zbuf, rowptr_m, ce_m, dinv_m,
                                       W_mg, b_mg, W_cls, b_cls, out, NM);
}